// Round 2
// baseline (2959.197 us; speedup 1.0000x reference)
//
#include <hip/hip_runtime.h>
#include <cfloat>

#define BZ    16384
#define KTOT  8192
#define DD    512
#define BM    64
#define BN    64
#define BK    32
#define NCHUNK (DD / BK)     // 16
#define NTILES (KTOT / BN)   // 128
#define LDT   68             // padded LDS stride (272 B, 16B-aligned rows, breaks bank conflicts)

// ---------------------------------------------------------------------------
// Kernel 1: e2[k] = sum(emb[k, :]^2). One wave per row, 4 rows per block.
// ---------------------------------------------------------------------------
__global__ void e2_kernel(const float* __restrict__ emb, float* __restrict__ e2) {
    const int row  = blockIdx.x * 4 + (threadIdx.x >> 6);
    const int lane = threadIdx.x & 63;
    const float4* p = reinterpret_cast<const float4*>(emb + (size_t)row * DD);
    float4 a = p[lane];
    float4 b = p[lane + 64];
    float s = a.x * a.x + a.y * a.y + a.z * a.z + a.w * a.w
            + b.x * b.x + b.y * b.y + b.z * b.z + b.w * b.w;
#pragma unroll
    for (int off = 32; off >= 1; off >>= 1) s += __shfl_down(s, off, 64);
    if (lane == 0) e2[row] = s;
}

// ---------------------------------------------------------------------------
// Kernel 2: fused fp32 GEMM (score = e2 - 2 x.e) + running argmin + gather.
// Block: 256 threads = 16x16, each thread owns a 4x4 micro-tile.
// BM=64 rows of x per block, loop over all 128 N-tiles of 64 embeddings.
// ---------------------------------------------------------------------------
__global__ __launch_bounds__(256) void vq_argmin_kernel(
    const float* __restrict__ x, const float* __restrict__ emb,
    const float* __restrict__ e2, float* __restrict__ out)
{
    __shared__ __align__(16) float xs[2][BK][LDT];  // [buf][k][m]
    __shared__ __align__(16) float es[2][BK][LDT];  // [buf][k][n]
    __shared__ float redv[BM][17];
    __shared__ int   redi[BM][17];
    __shared__ int   idx_s[BM];

    const int tid = threadIdx.x;
    const int tx  = tid & 15;       // column group (n)
    const int ty  = tid >> 4;       // row group (m)
    const int m0  = blockIdx.x * BM;

    // staging coords: 64 rows x 32 cols per chunk; each thread: 2 float4s
    const int srow = tid >> 3;            // 0..31
    const int scol = (tid & 7) << 2;      // 0,4,..,28

    const float* xb0 = x + (size_t)(m0 + srow) * DD + scol;
    const float* xb1 = xb0 + (size_t)32 * DD;

    float best[4];
    int   bidx[4];
#pragma unroll
    for (int i = 0; i < 4; ++i) { best[i] = FLT_MAX; bidx[i] = 0; }

#pragma unroll 1
    for (int nt = 0; nt < NTILES; ++nt) {
        const int n0 = nt * BN;
        const float* eb0 = emb + (size_t)(n0 + srow) * DD + scol;
        const float* eb1 = eb0 + (size_t)32 * DD;

        float acc[4][4];
#pragma unroll
        for (int i = 0; i < 4; ++i)
#pragma unroll
            for (int j = 0; j < 4; ++j) acc[i][j] = 0.f;

        // ---- prologue: stage chunk 0 into buf 0 ----
        {
            float4 xa = *(const float4*)(xb0);
            float4 xc = *(const float4*)(xb1);
            float4 ea = *(const float4*)(eb0);
            float4 ec = *(const float4*)(eb1);
#pragma unroll
            for (int i = 0; i < 4; ++i) {
                xs[0][scol + i][srow]      = ((const float*)&xa)[i];
                xs[0][scol + i][srow + 32] = ((const float*)&xc)[i];
                es[0][scol + i][srow]      = ((const float*)&ea)[i];
                es[0][scol + i][srow + 32] = ((const float*)&ec)[i];
            }
        }
        __syncthreads();

        int cur = 0;
#pragma unroll 1
        for (int kk = 1; kk < NCHUNK; ++kk) {
            // prefetch next chunk into registers (latency hides under compute)
            float4 nxa = *(const float4*)(xb0 + kk * BK);
            float4 nxc = *(const float4*)(xb1 + kk * BK);
            float4 nea = *(const float4*)(eb0 + kk * BK);
            float4 nec = *(const float4*)(eb1 + kk * BK);

#pragma unroll
            for (int k = 0; k < BK; ++k) {
                float4 a = *(const float4*)(&xs[cur][k][ty * 4]);
                float4 b = *(const float4*)(&es[cur][k][tx * 4]);
                acc[0][0] += a.x * b.x; acc[0][1] += a.x * b.y; acc[0][2] += a.x * b.z; acc[0][3] += a.x * b.w;
                acc[1][0] += a.y * b.x; acc[1][1] += a.y * b.y; acc[1][2] += a.y * b.z; acc[1][3] += a.y * b.w;
                acc[2][0] += a.z * b.x; acc[2][1] += a.z * b.y; acc[2][2] += a.z * b.z; acc[2][3] += a.z * b.w;
                acc[3][0] += a.w * b.x; acc[3][1] += a.w * b.y; acc[3][2] += a.w * b.z; acc[3][3] += a.w * b.w;
            }

            const int nb = cur ^ 1;
#pragma unroll
            for (int i = 0; i < 4; ++i) {
                xs[nb][scol + i][srow]      = ((const float*)&nxa)[i];
                xs[nb][scol + i][srow + 32] = ((const float*)&nxc)[i];
                es[nb][scol + i][srow]      = ((const float*)&nea)[i];
                es[nb][scol + i][srow + 32] = ((const float*)&nec)[i];
            }
            __syncthreads();
            cur = nb;
        }
        // ---- last chunk compute (no further staging) ----
#pragma unroll
        for (int k = 0; k < BK; ++k) {
            float4 a = *(const float4*)(&xs[cur][k][ty * 4]);
            float4 b = *(const float4*)(&es[cur][k][tx * 4]);
            acc[0][0] += a.x * b.x; acc[0][1] += a.x * b.y; acc[0][2] += a.x * b.z; acc[0][3] += a.x * b.w;
            acc[1][0] += a.y * b.x; acc[1][1] += a.y * b.y; acc[1][2] += a.y * b.z; acc[1][3] += a.y * b.w;
            acc[2][0] += a.z * b.x; acc[2][1] += a.z * b.y; acc[2][2] += a.z * b.z; acc[2][3] += a.z * b.w;
            acc[3][0] += a.w * b.x; acc[3][1] += a.w * b.y; acc[3][2] += a.w * b.z; acc[3][3] += a.w * b.w;
        }

        // ---- scores + running argmin (ascending n, strict <  => first occurrence) ----
#pragma unroll
        for (int j = 0; j < 4; ++j) {
            const int n  = n0 + tx * 4 + j;
            const float ee = e2[n];
#pragma unroll
            for (int i = 0; i < 4; ++i) {
                float s = ee - 2.0f * acc[i][j];
                if (s < best[i]) { best[i] = s; bidx[i] = n; }
            }
        }
        // NOTE: no barrier needed here — next prologue writes buf0, whose last
        // readers passed the kk=NCHUNK-1 barrier; buf1 readers don't alias.
    }

    // ---- cross-thread (tx) reduction per row: lexicographic (value, index) ----
#pragma unroll
    for (int i = 0; i < 4; ++i) {
        redv[ty * 4 + i][tx] = best[i];
        redi[ty * 4 + i][tx] = bidx[i];
    }
    __syncthreads();
    if (tid < BM) {
        float bv = redv[tid][0];
        int   bi = redi[tid][0];
#pragma unroll
        for (int t = 1; t < 16; ++t) {
            float v  = redv[tid][t];
            int   ii = redi[tid][t];
            if (v < bv || (v == bv && ii < bi)) { bv = v; bi = ii; }
        }
        idx_s[tid] = bi;
    }
    __syncthreads();

    // ---- fused gather: out[m0+r, :] = emb[idx_s[r], :] ----
    for (int c = tid; c < BM * (DD / 4); c += 256) {
        const int r   = c >> 7;            // DD/4 = 128 float4 per row
        const int col = (c & 127) << 2;
        const float4 v = *(const float4*)(emb + (size_t)idx_s[r] * DD + col);
        *(float4*)(out + (size_t)(m0 + r) * DD + col) = v;
    }
}

// ---------------------------------------------------------------------------
extern "C" void kernel_launch(void* const* d_in, const int* in_sizes, int n_in,
                              void* d_out, int out_size, void* d_ws, size_t ws_size,
                              hipStream_t stream) {
    const float* x   = (const float*)d_in[0];
    const float* emb = (const float*)d_in[1];
    float* out = (float*)d_out;
    float* e2  = (float*)d_ws;   // 8192 floats = 32 KB scratch

    e2_kernel<<<KTOT / 4, 256, 0, stream>>>(emb, e2);
    vq_argmin_kernel<<<BZ / BM, 256, 0, stream>>>(x, emb, e2, out);
}

// Round 5
// 818.470 us; speedup vs baseline: 3.6155x; 3.6155x over previous
//
#include <hip/hip_runtime.h>
#include <cfloat>

#define BZ    16384
#define KTOT  8192
#define DD    512
#define KK    1536          // [xh | xh | xl] . [eh | el | eh]
#define MARGIN 0.0625f

typedef unsigned long long u64;
typedef unsigned int       u32;
typedef __attribute__((ext_vector_type(8))) short bf16x8;
typedef __attribute__((ext_vector_type(4))) float f32x4;

// ---------------- helpers ----------------
__device__ __forceinline__ u32 f2bf_rne(float f) {           // fp32 -> bf16 bits (RNE)
    u32 b = __float_as_uint(f);
    return (b + 0x7FFFu + ((b >> 16) & 1u)) >> 16;
}
__device__ __forceinline__ float bf2f(u32 h) { return __uint_as_float(h << 16); }

__device__ __forceinline__ u64 pack_key(float s, int idx) {  // monotone (value, idx) key
    u32 b   = __float_as_uint(s);
    u32 key = (b & 0x80000000u) ? ~b : (b | 0x80000000u);
    return ((u64)key << 13) | (u32)idx;
}
__device__ __forceinline__ float unpack_val(u64 k) {
    u32 key = (u32)(k >> 13);
    u32 b   = (key & 0x80000000u) ? (key ^ 0x80000000u) : ~key;
    return __uint_as_float(b);
}

__device__ __forceinline__ void gload16(const void* g, void* l) {
    __builtin_amdgcn_global_load_lds(
        (const __attribute__((address_space(1))) void*)g,
        (__attribute__((address_space(3))) void*)l, 16, 0, 0);
}

// ---------------------------------------------------------------------------
// e2[k] = sum(emb[k,:]^2), fp32.
// ---------------------------------------------------------------------------
__global__ void e2_kernel(const float* __restrict__ emb, float* __restrict__ e2) {
    const int row  = blockIdx.x * 4 + (threadIdx.x >> 6);
    const int lane = threadIdx.x & 63;
    const float4* p = reinterpret_cast<const float4*>(emb + (size_t)row * DD);
    float4 a = p[lane];
    float4 b = p[lane + 64];
    float s = a.x * a.x + a.y * a.y + a.z * a.z + a.w * a.w
            + b.x * b.x + b.y * b.y + b.z * b.z + b.w * b.w;
#pragma unroll
    for (int off = 32; off >= 1; off >>= 1) s += __shfl_down(s, off, 64);
    if (lane == 0) e2[row] = s;
}

// ---------------------------------------------------------------------------
// Split kernels: build Xs = [xh | xh | xl], Es = [eh | el | eh]  (bf16)
// ---------------------------------------------------------------------------
__global__ void split_x_kernel(const float* __restrict__ x, ushort* __restrict__ Xs) {
    const size_t base = ((size_t)blockIdx.x * 256 + threadIdx.x) * 8;
    const int row = (int)(base >> 9);
    const int col = (int)(base & 511);
    float4 f0 = *(const float4*)(x + base);
    float4 f1 = *(const float4*)(x + base + 4);
    float ff[8] = {f0.x, f0.y, f0.z, f0.w, f1.x, f1.y, f1.z, f1.w};
    bf16x8 vh, vl;
#pragma unroll
    for (int j = 0; j < 8; ++j) {
        u32 hh = f2bf_rne(ff[j]);
        vh[j] = (short)hh;
        vl[j] = (short)f2bf_rne(ff[j] - bf2f(hh));
    }
    ushort* d = Xs + (size_t)row * KK;
    *(bf16x8*)(d + col)        = vh;
    *(bf16x8*)(d + 512 + col)  = vh;
    *(bf16x8*)(d + 1024 + col) = vl;
}

__global__ void split_e_kernel(const float* __restrict__ e, ushort* __restrict__ Es) {
    const size_t base = ((size_t)blockIdx.x * 256 + threadIdx.x) * 8;
    const int row = (int)(base >> 9);
    const int col = (int)(base & 511);
    float4 f0 = *(const float4*)(e + base);
    float4 f1 = *(const float4*)(e + base + 4);
    float ff[8] = {f0.x, f0.y, f0.z, f0.w, f1.x, f1.y, f1.z, f1.w};
    bf16x8 vh, vl;
#pragma unroll
    for (int j = 0; j < 8; ++j) {
        u32 hh = f2bf_rne(ff[j]);
        vh[j] = (short)hh;
        vl[j] = (short)f2bf_rne(ff[j] - bf2f(hh));
    }
    ushort* d = Es + (size_t)row * KK;
    *(bf16x8*)(d + col)        = vh;
    *(bf16x8*)(d + 512 + col)  = vl;
    *(bf16x8*)(d + 1024 + col) = vh;
}

// ---------------------------------------------------------------------------
// Screen: 128x128-tile MFMA GEMM over K'=1536, fused approx-score top-2.
// Grid: (BZ/128) x 8 N-splits = 1024 blocks, 256 threads (4 waves, 2x2 of 64x64).
// cand[row][32]: per (nsplit, wave-col) top-2 packed u64.
// ---------------------------------------------------------------------------
__global__ __launch_bounds__(256) void screen_kernel(
    const ushort* __restrict__ Xs, const ushort* __restrict__ Es,
    const float* __restrict__ e2, u64* __restrict__ cand)
{
    __shared__ __align__(16) ushort As[128 * 32];   // 8 KB, [row][k] linear
    __shared__ __align__(16) ushort Bs[128 * 32];   // 8 KB

    const int tid = threadIdx.x;
    const int ns  = blockIdx.x & 7;     // N-split id -> XCD affinity (round-robin)
    const int rb  = blockIdx.x >> 3;
    const int m0  = rb * 128;
    const int wid = tid >> 6;
    const int l   = tid & 63;
    const int wr  = wid >> 1, wc = wid & 1;
    const int lhi = l >> 4,   llo = l & 15;

    // staging coords: wave 'wid' instr i covers LDS rows (wid*2+i)*16..+15
    const int sr0 = (wid * 2 + 0) * 16 + (l >> 2);
    const int sr1 = (wid * 2 + 1) * 16 + (l >> 2);
    const int sc  = (l & 3) * 8;

    u64 t2a[16], t2b[16];
#pragma unroll
    for (int i = 0; i < 16; ++i) { t2a[i] = ~0ull; t2b[i] = ~0ull; }

#pragma unroll 1
    for (int nt = 0; nt < 8; ++nt) {
        const int n0 = ns * 1024 + nt * 128;
        f32x4 acc[4][4];
#pragma unroll
        for (int m = 0; m < 4; ++m)
#pragma unroll
            for (int n = 0; n < 4; ++n) acc[m][n] = (f32x4)(0.f);

#pragma unroll 1
        for (int ks = 0; ks < 48; ++ks) {
            const int k0 = ks * 32;
            __syncthreads();   // previous compute done reading LDS
            gload16(Xs + (size_t)(m0 + sr0) * KK + k0 + sc, &As[(wid * 2 + 0) * 512]);
            gload16(Xs + (size_t)(m0 + sr1) * KK + k0 + sc, &As[(wid * 2 + 1) * 512]);
            gload16(Es + (size_t)(n0 + sr0) * KK + k0 + sc, &Bs[(wid * 2 + 0) * 512]);
            gload16(Es + (size_t)(n0 + sr1) * KK + k0 + sc, &Bs[(wid * 2 + 1) * 512]);
            __syncthreads();   // vmcnt drained before barrier -> tiles ready

            bf16x8 a[4], b[4];
#pragma unroll
            for (int m = 0; m < 4; ++m)
                a[m] = *(const bf16x8*)&As[(wr * 64 + m * 16 + llo) * 32 + lhi * 8];
#pragma unroll
            for (int n = 0; n < 4; ++n)
                b[n] = *(const bf16x8*)&Bs[(wc * 64 + n * 16 + llo) * 32 + lhi * 8];
#pragma unroll
            for (int m = 0; m < 4; ++m)
#pragma unroll
                for (int n = 0; n < 4; ++n)
                    acc[m][n] = __builtin_amdgcn_mfma_f32_16x16x32_bf16(
                        a[m], b[n], acc[m][n], 0, 0, 0);
        }

        // approx scores + per-(lane,row) top-2.  C layout: col=llo, row=lhi*4+reg.
#pragma unroll
        for (int n = 0; n < 4; ++n) {
            const int col = n0 + wc * 64 + n * 16 + llo;
            const float ee = e2[col];
#pragma unroll
            for (int m = 0; m < 4; ++m)
#pragma unroll
                for (int r = 0; r < 4; ++r) {
                    float s = fmaf(-2.f, acc[m][n][r], ee);
                    u64 k = pack_key(s, col);
                    const int mr = m * 4 + r;
                    if (k < t2a[mr]) { t2b[mr] = t2a[mr]; t2a[mr] = k; }
                    else if (k < t2b[mr]) t2b[mr] = k;
                }
        }
    }

    // merge top-2 across the 16 lanes sharing lhi (xor masks stay in-group)
#pragma unroll
    for (int mr = 0; mr < 16; ++mr) {
        u64 a = t2a[mr], b = t2b[mr];
#pragma unroll
        for (int mask = 1; mask < 16; mask <<= 1) {
            u64 oa = __shfl_xor(a, mask, 64);
            u64 ob = __shfl_xor(b, mask, 64);
            u64 hi = a < oa ? oa : a;
            u64 lo2 = b < ob ? b : ob;
            a = a < oa ? a : oa;
            b = hi < lo2 ? hi : lo2;
        }
        if (llo == 0) {
            const int row = m0 + wr * 64 + (mr >> 2) * 16 + lhi * 4 + (mr & 3);
            cand[(size_t)row * 32 + ns * 4 + wc * 2 + 0] = a;
            cand[(size_t)row * 32 + ns * 4 + wc * 2 + 1] = b;
        }
    }
}

// ---------------------------------------------------------------------------
// Rescore + gather: one wave per row. Exact fp32 rescore only when ambiguous.
// ---------------------------------------------------------------------------
__global__ __launch_bounds__(256) void rescore_gather_kernel(
    const float* __restrict__ x, const float* __restrict__ emb,
    const float* __restrict__ e2, const u64* __restrict__ cand,
    float* __restrict__ out)
{
    const int tid = threadIdx.x;
    const int wid = tid >> 6, l = tid & 63;
    const int row = blockIdx.x * 4 + wid;

    u64 c = (l < 32) ? cand[(size_t)row * 32 + l] : ~0ull;
    u64 mn = c;
#pragma unroll
    for (int off = 32; off >= 1; off >>= 1) {
        u64 o = __shfl_xor(mn, off, 64);
        mn = o < mn ? o : mn;
    }
    const float vbest = unpack_val(mn);
    const float v = unpack_val(c);
    const bool amb = (l < 32) && (v <= vbest + MARGIN);
    u64 ball = __ballot(amb);

    int widx;
    if (__popcll(ball) <= 1) {
        widx = (int)(mn & 0x1FFFu);
    } else {
        u64 bestk = ~0ull;
        const float4* xp = (const float4*)(x + (size_t)row * DD);
        while (ball) {
            const int b = __ffsll((unsigned long long)ball) - 1;
            ball &= ball - 1;
            const int ib = __shfl((int)(c & 0x1FFFu), b, 64);
            const float4* ep = (const float4*)(emb + (size_t)ib * DD);
            float4 xa = xp[l],      ea = ep[l];
            float4 xb = xp[l + 64], eb = ep[l + 64];
            float s = xa.x * ea.x + xa.y * ea.y + xa.z * ea.z + xa.w * ea.w
                    + xb.x * eb.x + xb.y * eb.y + xb.z * eb.z + xb.w * eb.w;
#pragma unroll
            for (int off = 32; off >= 1; off >>= 1) s += __shfl_xor(s, off, 64);
            const float d = fmaf(-2.f, s, e2[ib]);
            u64 k = pack_key(d, ib);
            if (k < bestk) bestk = k;
        }
        widx = (int)(bestk & 0x1FFFu);
    }

    const float4* src = (const float4*)(emb + (size_t)widx * DD);
    float4* dst = (float4*)(out + (size_t)row * DD);
    dst[l]      = src[l];
    dst[l + 64] = src[l + 64];
}

// ===========================================================================
// Fallback fp32 path (proven-correct baseline) if ws is too small.
// ===========================================================================
#define BM 64
#define BN 64
#define BKf 32
#define NCHUNK (DD / BKf)
#define NTILES (KTOT / BN)
#define LDT 68

__global__ __launch_bounds__(256) void vq_argmin_kernel(
    const float* __restrict__ x, const float* __restrict__ emb,
    const float* __restrict__ e2, float* __restrict__ out)
{
    __shared__ __align__(16) float xs[2][BKf][LDT];
    __shared__ __align__(16) float es[2][BKf][LDT];
    __shared__ float redv[BM][17];
    __shared__ int   redi[BM][17];
    __shared__ int   idx_s[BM];

    const int tid = threadIdx.x;
    const int tx  = tid & 15;
    const int ty  = tid >> 4;
    const int m0  = blockIdx.x * BM;
    const int srow = tid >> 3;
    const int scol = (tid & 7) << 2;

    const float* xb0 = x + (size_t)(m0 + srow) * DD + scol;
    const float* xb1 = xb0 + (size_t)32 * DD;

    float best[4]; int bidx[4];
#pragma unroll
    for (int i = 0; i < 4; ++i) { best[i] = FLT_MAX; bidx[i] = 0; }

#pragma unroll 1
    for (int nt = 0; nt < NTILES; ++nt) {
        const int n0 = nt * BN;
        const float* eb0 = emb + (size_t)(n0 + srow) * DD + scol;
        const float* eb1 = eb0 + (size_t)32 * DD;
        float acc[4][4];
#pragma unroll
        for (int i = 0; i < 4; ++i)
#pragma unroll
            for (int j = 0; j < 4; ++j) acc[i][j] = 0.f;
        {
            float4 xa = *(const float4*)(xb0);
            float4 xc = *(const float4*)(xb1);
            float4 ea = *(const float4*)(eb0);
            float4 ec = *(const float4*)(eb1);
#pragma unroll
            for (int i = 0; i < 4; ++i) {
                xs[0][scol + i][srow]      = ((const float*)&xa)[i];
                xs[0][scol + i][srow + 32] = ((const float*)&xc)[i];
                es[0][scol + i][srow]      = ((const float*)&ea)[i];
                es[0][scol + i][srow + 32] = ((const float*)&ec)[i];
            }
        }
        __syncthreads();
        int cur = 0;
#pragma unroll 1
        for (int kk = 1; kk < NCHUNK; ++kk) {
            float4 nxa = *(const float4*)(xb0 + kk * BKf);
            float4 nxc = *(const float4*)(xb1 + kk * BKf);
            float4 nea = *(const float4*)(eb0 + kk * BKf);
            float4 nec = *(const float4*)(eb1 + kk * BKf);
#pragma unroll
            for (int k = 0; k < BKf; ++k) {
                float4 a = *(const float4*)(&xs[cur][k][ty * 4]);
                float4 b = *(const float4*)(&es[cur][k][tx * 4]);
                acc[0][0] += a.x * b.x; acc[0][1] += a.x * b.y; acc[0][2] += a.x * b.z; acc[0][3] += a.x * b.w;
                acc[1][0] += a.y * b.x; acc[1][1] += a.y * b.y; acc[1][2] += a.y * b.z; acc[1][3] += a.y * b.w;
                acc[2][0] += a.z * b.x; acc[2][1] += a.z * b.y; acc[2][2] += a.z * b.z; acc[2][3] += a.z * b.w;
                acc[3][0] += a.w * b.x; acc[3][1] += a.w * b.y; acc[3][2] += a.w * b.z; acc[3][3] += a.w * b.w;
            }
            const int nb = cur ^ 1;
#pragma unroll
            for (int i = 0; i < 4; ++i) {
                xs[nb][scol + i][srow]      = ((const float*)&nxa)[i];
                xs[nb][scol + i][srow + 32] = ((const float*)&nxc)[i];
                es[nb][scol + i][srow]      = ((const float*)&nea)[i];
                es[nb][scol + i][srow + 32] = ((const float*)&nec)[i];
            }
            __syncthreads();
            cur = nb;
        }
#pragma unroll
        for (int k = 0; k < BKf; ++k) {
            float4 a = *(const float4*)(&xs[cur][k][ty * 4]);
            float4 b = *(const float4*)(&es[cur][k][tx * 4]);
            acc[0][0] += a.x * b.x; acc[0][1] += a.x * b.y; acc[0][2] += a.x * b.z; acc[0][3] += a.x * b.w;
            acc[1][0] += a.y * b.x; acc[1][1] += a.y * b.y; acc[1][2] += a.y * b.z; acc[1][3] += a.y * b.w;
            acc[2][0] += a.z * b.x; acc[2][1] += a.z * b.y; acc[2][2] += a.z * b.z; acc[2][3] += a.z * b.w;
            acc[3][0] += a.w * b.x; acc[3][1] += a.w * b.y; acc[3][2] += a.w * b.z; acc[3][3] += a.w * b.w;
        }
#pragma unroll
        for (int j = 0; j < 4; ++j) {
            const int n  = n0 + tx * 4 + j;
            const float ee = e2[n];
#pragma unroll
            for (int i = 0; i < 4; ++i) {
                float s = ee - 2.0f * acc[i][j];
                if (s < best[i]) { best[i] = s; bidx[i] = n; }
            }
        }
    }
#pragma unroll
    for (int i = 0; i < 4; ++i) {
        redv[ty * 4 + i][tx] = best[i];
        redi[ty * 4 + i][tx] = bidx[i];
    }
    __syncthreads();
    if (tid < BM) {
        float bv = redv[tid][0];
        int   bi = redi[tid][0];
#pragma unroll
        for (int t = 1; t < 16; ++t) {
            float v  = redv[tid][t];
            int   ii = redi[tid][t];
            if (v < bv || (v == bv && ii < bi)) { bv = v; bi = ii; }
        }
        idx_s[tid] = bi;
    }
    __syncthreads();
    for (int c = tid; c < BM * (DD / 4); c += 256) {
        const int r   = c >> 7;
        const int col = (c & 127) << 2;
        const float4 vv = *(const float4*)(emb + (size_t)idx_s[r] * DD + col);
        *(float4*)(out + (size_t)(m0 + r) * DD + col) = vv;
    }
}

// ---------------------------------------------------------------------------
extern "C" void kernel_launch(void* const* d_in, const int* in_sizes, int n_in,
                              void* d_out, int out_size, void* d_ws, size_t ws_size,
                              hipStream_t stream) {
    const float* x   = (const float*)d_in[0];
    const float* emb = (const float*)d_in[1];
    float* out = (float*)d_out;

    const size_t XS_BYTES   = (size_t)BZ * KK * 2;       // 50331648
    const size_t ES_BYTES   = (size_t)KTOT * KK * 2;     // 25165824
    const size_t E2_BYTES   = (size_t)KTOT * 4;          // 32768
    const size_t CAND_BYTES = (size_t)BZ * 32 * 8;       // 4194304
    const size_t NEEDED = XS_BYTES + ES_BYTES + E2_BYTES + CAND_BYTES;

    if (ws_size >= NEEDED) {
        char* base = (char*)d_ws;
        ushort* Xs = (ushort*)base;
        ushort* Es = (ushort*)(base + XS_BYTES);
        float*  e2 = (float*)(base + XS_BYTES + ES_BYTES);
        u64*  cand = (u64*)(base + XS_BYTES + ES_BYTES + E2_BYTES);

        split_x_kernel<<<(BZ * DD) / (256 * 8), 256, 0, stream>>>(x, Xs);
        split_e_kernel<<<(KTOT * DD) / (256 * 8), 256, 0, stream>>>(emb, Es);
        e2_kernel<<<KTOT / 4, 256, 0, stream>>>(emb, e2);
        screen_kernel<<<(BZ / 128) * 8, 256, 0, stream>>>(Xs, Es, e2, cand);
        rescore_gather_kernel<<<BZ / 4, 256, 0, stream>>>(x, emb, e2, cand, out);
    } else {
        float* e2 = (float*)d_ws;
        e2_kernel<<<KTOT / 4, 256, 0, stream>>>(emb, e2);
        vq_argmin_kernel<<<BZ / BM, 256, 0, stream>>>(x, emb, e2, out);
    }
}

// Round 6
// 379.260 us; speedup vs baseline: 7.8026x; 2.1581x over previous
//
#include <hip/hip_runtime.h>
#include <cfloat>

#define BZ    16384
#define KTOT  8192
#define DD    512
#define KK    512           // plain bf16 screen GEMM (was 1536 bf16x3)
#define MARGIN 2.0f         // ~28 sigma of bf16 score error; gaps ~Exp(39)

typedef unsigned long long u64;
typedef unsigned int       u32;
typedef __attribute__((ext_vector_type(8))) short bf16x8;
typedef __attribute__((ext_vector_type(4))) short bf16x4;
typedef __attribute__((ext_vector_type(4))) float f32x4;

// ---------------- helpers ----------------
__device__ __forceinline__ u32 f2bf_rne(float f) {           // fp32 -> bf16 bits (RNE)
    u32 b = __float_as_uint(f);
    return (b + 0x7FFFu + ((b >> 16) & 1u)) >> 16;
}

__device__ __forceinline__ u64 pack_key(float s, int idx) {  // monotone (value, idx) key
    u32 b   = __float_as_uint(s);
    u32 key = (b & 0x80000000u) ? ~b : (b | 0x80000000u);
    return ((u64)key << 13) | (u32)idx;
}
__device__ __forceinline__ float unpack_val(u64 k) {
    u32 key = (u32)(k >> 13);
    u32 b   = (key & 0x80000000u) ? (key ^ 0x80000000u) : ~key;
    return __uint_as_float(b);
}

__device__ __forceinline__ void gload16(const void* g, void* l) {
    __builtin_amdgcn_global_load_lds(
        (const __attribute__((address_space(1))) void*)g,
        (__attribute__((address_space(3))) void*)l, 16, 0, 0);
}

// ---------------------------------------------------------------------------
// cast x -> bf16 (Xs). 8 elems/thread.
// ---------------------------------------------------------------------------
__global__ void cast_x_kernel(const float* __restrict__ x, ushort* __restrict__ Xs) {
    const size_t base = ((size_t)blockIdx.x * 256 + threadIdx.x) * 8;
    float4 f0 = *(const float4*)(x + base);
    float4 f1 = *(const float4*)(x + base + 4);
    float ff[8] = {f0.x, f0.y, f0.z, f0.w, f1.x, f1.y, f1.z, f1.w};
    bf16x8 vh;
#pragma unroll
    for (int j = 0; j < 8; ++j) vh[j] = (short)f2bf_rne(ff[j]);
    *(bf16x8*)(Xs + base) = vh;
}

// ---------------------------------------------------------------------------
// fused: Es = bf16(emb), e2[k] = sum(emb[k,:]^2).  One wave per row.
// ---------------------------------------------------------------------------
__global__ void cast_e_e2_kernel(const float* __restrict__ emb,
                                 ushort* __restrict__ Es, float* __restrict__ e2) {
    const int row  = blockIdx.x * 4 + (threadIdx.x >> 6);
    const int lane = threadIdx.x & 63;
    const float4* p = reinterpret_cast<const float4*>(emb + (size_t)row * DD);
    float4 a = p[lane];
    float4 b = p[lane + 64];
    bf16x4 ha, hb;
    ha[0] = (short)f2bf_rne(a.x); ha[1] = (short)f2bf_rne(a.y);
    ha[2] = (short)f2bf_rne(a.z); ha[3] = (short)f2bf_rne(a.w);
    hb[0] = (short)f2bf_rne(b.x); hb[1] = (short)f2bf_rne(b.y);
    hb[2] = (short)f2bf_rne(b.z); hb[3] = (short)f2bf_rne(b.w);
    ushort* d = Es + (size_t)row * DD;
    *(bf16x4*)(d + lane * 4)       = ha;
    *(bf16x4*)(d + 256 + lane * 4) = hb;
    float s = a.x * a.x + a.y * a.y + a.z * a.z + a.w * a.w
            + b.x * b.x + b.y * b.y + b.z * b.z + b.w * b.w;
#pragma unroll
    for (int off = 32; off >= 1; off >>= 1) s += __shfl_down(s, off, 64);
    if (lane == 0) e2[row] = s;
}

// ---------------------------------------------------------------------------
// Screen: 128x128-tile bf16 MFMA GEMM over K=512, fused approx-score top-2.
// Grid: (BZ/128) x 8 N-splits = 1024 blocks, 256 threads (4 waves, 2x2 of 64x64).
// cand[row][32]: per (nsplit, wave-col) top-2 packed u64.
// ---------------------------------------------------------------------------
__global__ __launch_bounds__(256) void screen_kernel(
    const ushort* __restrict__ Xs, const ushort* __restrict__ Es,
    const float* __restrict__ e2, u64* __restrict__ cand)
{
    __shared__ __align__(16) ushort As[128 * 32];   // 8 KB, [row][k] linear
    __shared__ __align__(16) ushort Bs[128 * 32];   // 8 KB

    const int tid = threadIdx.x;
    const int ns  = blockIdx.x & 7;     // N-split id -> XCD affinity (round-robin)
    const int rb  = blockIdx.x >> 3;
    const int m0  = rb * 128;
    const int wid = tid >> 6;
    const int l   = tid & 63;
    const int wr  = wid >> 1, wc = wid & 1;
    const int lhi = l >> 4,   llo = l & 15;

    // staging coords: wave 'wid' instr i covers LDS rows (wid*2+i)*16..+15
    const int sr0 = (wid * 2 + 0) * 16 + (l >> 2);
    const int sr1 = (wid * 2 + 1) * 16 + (l >> 2);
    const int sc  = (l & 3) * 8;

    u64 t2a[16], t2b[16];
#pragma unroll
    for (int i = 0; i < 16; ++i) { t2a[i] = ~0ull; t2b[i] = ~0ull; }

#pragma unroll 1
    for (int nt = 0; nt < 8; ++nt) {
        const int n0 = ns * 1024 + nt * 128;
        f32x4 acc[4][4];
#pragma unroll
        for (int m = 0; m < 4; ++m)
#pragma unroll
            for (int n = 0; n < 4; ++n) acc[m][n] = (f32x4)(0.f);

#pragma unroll 1
        for (int ks = 0; ks < 16; ++ks) {
            const int k0 = ks * 32;
            __syncthreads();   // previous compute done reading LDS
            gload16(Xs + (size_t)(m0 + sr0) * KK + k0 + sc, &As[(wid * 2 + 0) * 512]);
            gload16(Xs + (size_t)(m0 + sr1) * KK + k0 + sc, &As[(wid * 2 + 1) * 512]);
            gload16(Es + (size_t)(n0 + sr0) * KK + k0 + sc, &Bs[(wid * 2 + 0) * 512]);
            gload16(Es + (size_t)(n0 + sr1) * KK + k0 + sc, &Bs[(wid * 2 + 1) * 512]);
            __syncthreads();   // vmcnt drained before barrier -> tiles ready

            bf16x8 a[4], b[4];
#pragma unroll
            for (int m = 0; m < 4; ++m)
                a[m] = *(const bf16x8*)&As[(wr * 64 + m * 16 + llo) * 32 + lhi * 8];
#pragma unroll
            for (int n = 0; n < 4; ++n)
                b[n] = *(const bf16x8*)&Bs[(wc * 64 + n * 16 + llo) * 32 + lhi * 8];
#pragma unroll
            for (int m = 0; m < 4; ++m)
#pragma unroll
                for (int n = 0; n < 4; ++n)
                    acc[m][n] = __builtin_amdgcn_mfma_f32_16x16x32_bf16(
                        a[m], b[n], acc[m][n], 0, 0, 0);
        }

        // approx scores + per-(lane,row) top-2.  C layout: col=llo, row=lhi*4+reg.
#pragma unroll
        for (int n = 0; n < 4; ++n) {
            const int col = n0 + wc * 64 + n * 16 + llo;
            const float ee = e2[col];
#pragma unroll
            for (int m = 0; m < 4; ++m)
#pragma unroll
                for (int r = 0; r < 4; ++r) {
                    float s = fmaf(-2.f, acc[m][n][r], ee);
                    u64 k = pack_key(s, col);
                    const int mr = m * 4 + r;
                    if (k < t2a[mr]) { t2b[mr] = t2a[mr]; t2a[mr] = k; }
                    else if (k < t2b[mr]) t2b[mr] = k;
                }
        }
    }

    // merge top-2 across the 16 lanes sharing lhi (xor masks stay in-group)
#pragma unroll
    for (int mr = 0; mr < 16; ++mr) {
        u64 a = t2a[mr], b = t2b[mr];
#pragma unroll
        for (int mask = 1; mask < 16; mask <<= 1) {
            u64 oa = __shfl_xor(a, mask, 64);
            u64 ob = __shfl_xor(b, mask, 64);
            u64 hi = a < oa ? oa : a;
            u64 lo2 = b < ob ? b : ob;
            a = a < oa ? a : oa;
            b = hi < lo2 ? hi : lo2;
        }
        if (llo == 0) {
            const int row = m0 + wr * 64 + (mr >> 2) * 16 + lhi * 4 + (mr & 3);
            cand[(size_t)row * 32 + ns * 4 + wc * 2 + 0] = a;
            cand[(size_t)row * 32 + ns * 4 + wc * 2 + 1] = b;
        }
    }
}

// ---------------------------------------------------------------------------
// Rescore + gather: one wave per row. Exact fp32 rescore only when ambiguous.
// ---------------------------------------------------------------------------
__global__ __launch_bounds__(256) void rescore_gather_kernel(
    const float* __restrict__ x, const float* __restrict__ emb,
    const float* __restrict__ e2, const u64* __restrict__ cand,
    float* __restrict__ out)
{
    const int tid = threadIdx.x;
    const int wid = tid >> 6, l = tid & 63;
    const int row = blockIdx.x * 4 + wid;

    u64 c = (l < 32) ? cand[(size_t)row * 32 + l] : ~0ull;
    u64 mn = c;
#pragma unroll
    for (int off = 32; off >= 1; off >>= 1) {
        u64 o = __shfl_xor(mn, off, 64);
        mn = o < mn ? o : mn;
    }
    const float vbest = unpack_val(mn);
    const float v = unpack_val(c);
    const bool amb = (l < 32) && (v <= vbest + MARGIN);
    u64 ball = __ballot(amb);

    int widx;
    if (__popcll(ball) <= 1) {
        widx = (int)(mn & 0x1FFFu);
    } else {
        u64 bestk = ~0ull;
        const float4* xp = (const float4*)(x + (size_t)row * DD);
        while (ball) {
            const int b = __ffsll((unsigned long long)ball) - 1;
            ball &= ball - 1;
            const int ib = __shfl((int)(c & 0x1FFFu), b, 64);
            const float4* ep = (const float4*)(emb + (size_t)ib * DD);
            float4 xa = xp[l],      ea = ep[l];
            float4 xb = xp[l + 64], eb = ep[l + 64];
            float s = xa.x * ea.x + xa.y * ea.y + xa.z * ea.z + xa.w * ea.w
                    + xb.x * eb.x + xb.y * eb.y + xb.z * eb.z + xb.w * eb.w;
#pragma unroll
            for (int off = 32; off >= 1; off >>= 1) s += __shfl_xor(s, off, 64);
            const float d = fmaf(-2.f, s, e2[ib]);
            u64 k = pack_key(d, ib);
            if (k < bestk) bestk = k;
        }
        widx = (int)(bestk & 0x1FFFu);
    }

    const float4* src = (const float4*)(emb + (size_t)widx * DD);
    float4* dst = (float4*)(out + (size_t)row * DD);
    dst[l]      = src[l];
    dst[l + 64] = src[l + 64];
}

// ===========================================================================
// Fallback fp32 path (proven-correct baseline) if ws is too small.
// ===========================================================================
#define BM 64
#define BN 64
#define BKf 32
#define NCHUNKf (DD / BKf)
#define NTILESf (KTOT / BN)
#define LDT 68

__global__ void e2_only_kernel(const float* __restrict__ emb, float* __restrict__ e2) {
    const int row  = blockIdx.x * 4 + (threadIdx.x >> 6);
    const int lane = threadIdx.x & 63;
    const float4* p = reinterpret_cast<const float4*>(emb + (size_t)row * DD);
    float4 a = p[lane];
    float4 b = p[lane + 64];
    float s = a.x * a.x + a.y * a.y + a.z * a.z + a.w * a.w
            + b.x * b.x + b.y * b.y + b.z * b.z + b.w * b.w;
#pragma unroll
    for (int off = 32; off >= 1; off >>= 1) s += __shfl_down(s, off, 64);
    if (lane == 0) e2[row] = s;
}

__global__ __launch_bounds__(256) void vq_argmin_kernel(
    const float* __restrict__ x, const float* __restrict__ emb,
    const float* __restrict__ e2, float* __restrict__ out)
{
    __shared__ __align__(16) float xs[2][BKf][LDT];
    __shared__ __align__(16) float es[2][BKf][LDT];
    __shared__ float redv[BM][17];
    __shared__ int   redi[BM][17];
    __shared__ int   idx_s[BM];

    const int tid = threadIdx.x;
    const int tx  = tid & 15;
    const int ty  = tid >> 4;
    const int m0  = blockIdx.x * BM;
    const int srow = tid >> 3;
    const int scol = (tid & 7) << 2;

    const float* xb0 = x + (size_t)(m0 + srow) * DD + scol;
    const float* xb1 = xb0 + (size_t)32 * DD;

    float best[4]; int bidx[4];
#pragma unroll
    for (int i = 0; i < 4; ++i) { best[i] = FLT_MAX; bidx[i] = 0; }

#pragma unroll 1
    for (int nt = 0; nt < NTILESf; ++nt) {
        const int n0 = nt * BN;
        const float* eb0 = emb + (size_t)(n0 + srow) * DD + scol;
        const float* eb1 = eb0 + (size_t)32 * DD;
        float acc[4][4];
#pragma unroll
        for (int i = 0; i < 4; ++i)
#pragma unroll
            for (int j = 0; j < 4; ++j) acc[i][j] = 0.f;
        {
            float4 xa = *(const float4*)(xb0);
            float4 xc = *(const float4*)(xb1);
            float4 ea = *(const float4*)(eb0);
            float4 ec = *(const float4*)(eb1);
#pragma unroll
            for (int i = 0; i < 4; ++i) {
                xs[0][scol + i][srow]      = ((const float*)&xa)[i];
                xs[0][scol + i][srow + 32] = ((const float*)&xc)[i];
                es[0][scol + i][srow]      = ((const float*)&ea)[i];
                es[0][scol + i][srow + 32] = ((const float*)&ec)[i];
            }
        }
        __syncthreads();
        int cur = 0;
#pragma unroll 1
        for (int kk = 1; kk < NCHUNKf; ++kk) {
            float4 nxa = *(const float4*)(xb0 + kk * BKf);
            float4 nxc = *(const float4*)(xb1 + kk * BKf);
            float4 nea = *(const float4*)(eb0 + kk * BKf);
            float4 nec = *(const float4*)(eb1 + kk * BKf);
#pragma unroll
            for (int k = 0; k < BKf; ++k) {
                float4 a = *(const float4*)(&xs[cur][k][ty * 4]);
                float4 b = *(const float4*)(&es[cur][k][tx * 4]);
                acc[0][0] += a.x * b.x; acc[0][1] += a.x * b.y; acc[0][2] += a.x * b.z; acc[0][3] += a.x * b.w;
                acc[1][0] += a.y * b.x; acc[1][1] += a.y * b.y; acc[1][2] += a.y * b.z; acc[1][3] += a.y * b.w;
                acc[2][0] += a.z * b.x; acc[2][1] += a.z * b.y; acc[2][2] += a.z * b.z; acc[2][3] += a.z * b.w;
                acc[3][0] += a.w * b.x; acc[3][1] += a.w * b.y; acc[3][2] += a.w * b.z; acc[3][3] += a.w * b.w;
            }
            const int nb = cur ^ 1;
#pragma unroll
            for (int i = 0; i < 4; ++i) {
                xs[nb][scol + i][srow]      = ((const float*)&nxa)[i];
                xs[nb][scol + i][srow + 32] = ((const float*)&nxc)[i];
                es[nb][scol + i][srow]      = ((const float*)&nea)[i];
                es[nb][scol + i][srow + 32] = ((const float*)&nec)[i];
            }
            __syncthreads();
            cur = nb;
        }
#pragma unroll
        for (int k = 0; k < BKf; ++k) {
            float4 a = *(const float4*)(&xs[cur][k][ty * 4]);
            float4 b = *(const float4*)(&es[cur][k][tx * 4]);
            acc[0][0] += a.x * b.x; acc[0][1] += a.x * b.y; acc[0][2] += a.x * b.z; acc[0][3] += a.x * b.w;
            acc[1][0] += a.y * b.x; acc[1][1] += a.y * b.y; acc[1][2] += a.y * b.z; acc[1][3] += a.y * b.w;
            acc[2][0] += a.z * b.x; acc[2][1] += a.z * b.y; acc[2][2] += a.z * b.z; acc[2][3] += a.z * b.w;
            acc[3][0] += a.w * b.x; acc[3][1] += a.w * b.y; acc[3][2] += a.w * b.z; acc[3][3] += a.w * b.w;
        }
#pragma unroll
        for (int j = 0; j < 4; ++j) {
            const int n  = n0 + tx * 4 + j;
            const float ee = e2[n];
#pragma unroll
            for (int i = 0; i < 4; ++i) {
                float s = ee - 2.0f * acc[i][j];
                if (s < best[i]) { best[i] = s; bidx[i] = n; }
            }
        }
    }
#pragma unroll
    for (int i = 0; i < 4; ++i) {
        redv[ty * 4 + i][tx] = best[i];
        redi[ty * 4 + i][tx] = bidx[i];
    }
    __syncthreads();
    if (tid < BM) {
        float bv = redv[tid][0];
        int   bi = redi[tid][0];
#pragma unroll
        for (int t = 1; t < 16; ++t) {
            float v  = redv[tid][t];
            int   ii = redi[tid][t];
            if (v < bv || (v == bv && ii < bi)) { bv = v; bi = ii; }
        }
        idx_s[tid] = bi;
    }
    __syncthreads();
    for (int c = tid; c < BM * (DD / 4); c += 256) {
        const int r   = c >> 7;
        const int col = (c & 127) << 2;
        const float4 vv = *(const float4*)(emb + (size_t)idx_s[r] * DD + col);
        *(float4*)(out + (size_t)(m0 + r) * DD + col) = vv;
    }
}

// ---------------------------------------------------------------------------
extern "C" void kernel_launch(void* const* d_in, const int* in_sizes, int n_in,
                              void* d_out, int out_size, void* d_ws, size_t ws_size,
                              hipStream_t stream) {
    const float* x   = (const float*)d_in[0];
    const float* emb = (const float*)d_in[1];
    float* out = (float*)d_out;

    const size_t XS_BYTES   = (size_t)BZ * KK * 2;       // 16 MB
    const size_t ES_BYTES   = (size_t)KTOT * KK * 2;     // 8 MB
    const size_t E2_BYTES   = (size_t)KTOT * 4;          // 32 KB
    const size_t CAND_BYTES = (size_t)BZ * 32 * 8;       // 4 MB
    const size_t NEEDED = XS_BYTES + ES_BYTES + E2_BYTES + CAND_BYTES;

    if (ws_size >= NEEDED) {
        char* base = (char*)d_ws;
        ushort* Xs = (ushort*)base;
        ushort* Es = (ushort*)(base + XS_BYTES);
        float*  e2 = (float*)(base + XS_BYTES + ES_BYTES);
        u64*  cand = (u64*)(base + XS_BYTES + ES_BYTES + E2_BYTES);

        cast_x_kernel<<<(BZ * DD) / (256 * 8), 256, 0, stream>>>(x, Xs);
        cast_e_e2_kernel<<<KTOT / 4, 256, 0, stream>>>(emb, Es, e2);
        screen_kernel<<<(BZ / 128) * 8, 256, 0, stream>>>(Xs, Es, e2, cand);
        rescore_gather_kernel<<<BZ / 4, 256, 0, stream>>>(x, emb, e2, cand, out);
    } else {
        float* e2 = (float*)d_ws;
        e2_only_kernel<<<KTOT / 4, 256, 0, stream>>>(emb, e2);
        vq_argmin_kernel<<<BZ / BM, 256, 0, stream>>>(x, emb, e2, out);
    }
}